// Round 3
// baseline (111.963 us; speedup 1.0000x reference)
//
#include <hip/hip_runtime.h>
#include <hip/hip_bf16.h>
#include <hip/hip_fp16.h>

typedef _Float16 f16x8 __attribute__((ext_vector_type(8)));
typedef float f32x4 __attribute__((ext_vector_type(4)));

#define N_PTS 32768
#define NCHUNK 65       // 64 h-chunks + 1 bias chunk (h == 1)
#define ROWS 64         // rows per block
#define P_STRIDE 65     // odd stride: scalar reduce traffic <=2-way bank alias
#define P_BUF (ROWS * P_STRIDE)

// ---- prep: convert W2 (fp32 [4096][64]) and b2 (fp32 [4096]) into f16
// fragment-major layout in ws. Source-coalesced: thread t reads element t.
//   src index t = kk*64 + o  (kk = c*64 + kl, chunk c==64 is b2)
//   dest = (((c*2+s)*4+nt)*64 + lane)*8 + j
//   with s=kl>>5, j=kl&7, lane=(((kl>>3)&3)<<4)|(o&15), nt=o>>4
__global__ void prep_kernel(const float* __restrict__ W2,
                            const float* __restrict__ b2,
                            _Float16* __restrict__ wsB) {
    int t = blockIdx.x * blockDim.x + threadIdx.x;
    if (t >= NCHUNK * 4096) return;
    int kk = t >> 6, o = t & 63;
    float v = (kk < 4096) ? W2[t] : b2[t - 4096 * 64];
    int c = kk >> 6, kl = kk & 63;
    int s = kl >> 5, j = kl & 7;
    int lane = (((kl >> 3) & 3) << 4) | (o & 15);
    int nt = o >> 4;
    wsB[(((c * 2 + s) * 4 + nt) * 64 + lane) * 8 + j] = (_Float16)v;
}

// ---- main fused kernel ----
// 512 blocks x 512 threads (8 waves). Block owns 64 rows; waves K-split the
// 65 chunks 8-way (wave w: c = w, w+8, ...), partials reduced via LDS 2-stage.
__global__ __launch_bounds__(512, 4) void main_kernel(
    const float* __restrict__ x, const float* __restrict__ gridp,
    const float* __restrict__ W1, const float* __restrict__ b1,
    const _Float16* __restrict__ wsB, float* __restrict__ out) {

  __shared__ _Float16 h_lds[ROWS][66];   // 8448 B
  __shared__ float part[4][P_BUF];       // 66560 B ; total 75008 <= 81920

  const int tid  = threadIdx.x;
  const int lane = tid & 63;
  const int wave = tid >> 6;
  const int rowblk = blockIdx.x * ROWS;

  // phase 1: h[row][k] = gelu(grid @ W1 + b1). 8 threads/row, 8 k each.
  {
    int row = tid >> 3;
    int kb  = (tid & 7) * 8;
    int r = rowblk + row;
    float g0 = gridp[r * 3 + 0], g1 = gridp[r * 3 + 1], g2 = gridp[r * 3 + 2];
    f32x4 wa0 = *(const f32x4*)(W1 + kb),       wa1 = *(const f32x4*)(W1 + kb + 4);
    f32x4 wb0 = *(const f32x4*)(W1 + 64 + kb),  wb1 = *(const f32x4*)(W1 + 64 + kb + 4);
    f32x4 wc0 = *(const f32x4*)(W1 + 128 + kb), wc1 = *(const f32x4*)(W1 + 128 + kb + 4);
    f32x4 bb0 = *(const f32x4*)(b1 + kb),       bb1 = *(const f32x4*)(b1 + kb + 4);
    #pragma unroll
    for (int q = 0; q < 8; ++q) {
      float v = (q < 4)
        ? g0 * wa0[q] + g1 * wb0[q] + g2 * wc0[q] + bb0[q]
        : g0 * wa1[q - 4] + g1 * wb1[q - 4] + g2 * wc1[q - 4] + bb1[q - 4];
      float h = 0.5f * v * (1.0f + erff(v * 0.7071067811865476f));
      h_lds[row][kb + q] = (_Float16)h;
    }
    if ((tid & 7) == 7) h_lds[row][64] = (_Float16)1.0f;  // bias chunk: h == 1
  }
  __syncthreads();

  const int mrow = lane & 15;        // A row within 16-tile / D col
  const int kgrp = lane >> 4;        // 0..3

  // x fragments: xf[m][s][j] = x[row, s*32 + kgrp*8 + j]  (fixed across K loop)
  f16x8 xf[4][2];
  #pragma unroll
  for (int m = 0; m < 4; ++m) {
    #pragma unroll
    for (int s = 0; s < 2; ++s) {
      const float* xp = x + (rowblk + m * 16 + mrow) * 64 + s * 32 + kgrp * 8;
      f16x8 v;
      #pragma unroll
      for (int j = 0; j < 8; ++j) v[j] = (_Float16)xp[j];
      xf[m][s] = v;
    }
  }

  f32x4 acc[4][4];
  #pragma unroll
  for (int m = 0; m < 4; ++m)
    #pragma unroll
    for (int n = 0; n < 4; ++n)
      acc[m][n] = (f32x4){0.f, 0.f, 0.f, 0.f};

  const _Float16* bp = wsB + lane * 8;   // + (c*8 + q)*512 elements

  auto LOADB = [&](f16x8* b, int c) {
    #pragma unroll
    for (int q = 0; q < 8; ++q)
      b[q] = *(const f16x8*)(bp + (c * 8 + q) * 512);
  };
  auto COMPUTE = [&](const f16x8* b, int c) {
    #pragma unroll
    for (int m = 0; m < 4; ++m) {
      _Float16 hh = h_lds[m * 16 + mrow][c];
      f16x8 hs = {hh, hh, hh, hh, hh, hh, hh, hh};
      f16x8 a0 = xf[m][0] * hs;   // v_pk_mul_f16: A-frag = h_k * x-frag
      f16x8 a1 = xf[m][1] * hs;
      #pragma unroll
      for (int n = 0; n < 4; ++n) {
        acc[m][n] = __builtin_amdgcn_mfma_f32_16x16x32_f16(a0, b[n],     acc[m][n], 0, 0, 0);
        acc[m][n] = __builtin_amdgcn_mfma_f32_16x16x32_f16(a1, b[4 + n], acc[m][n], 0, 0, 0);
      }
    }
  };

  // K-split: wave w handles chunks c = w, w+8, ... (< 65). wave0 gets 9.
  const int nch = (wave == 0) ? 9 : 8;
  f16x8 bufA[8], bufB[8];
  LOADB(bufA, wave);
  int i = 1;
  for (; i + 1 < nch; i += 2) {
    LOADB(bufB, wave + 8 * i);
    COMPUTE(bufA, wave + 8 * (i - 1));
    LOADB(bufA, wave + 8 * (i + 1));   // max c = 64 (wave 0) : in range
    COMPUTE(bufB, wave + 8 * i);
  }
  if (i < nch) {                       // nch even (8): tail pair
    LOADB(bufB, wave + 8 * i);
    COMPUTE(bufA, wave + 8 * (i - 1));
    COMPUTE(bufB, wave + 8 * i);
  } else {                             // nch odd (9, wave 0)
    COMPUTE(bufA, wave + 8 * (nch - 1));
  }

  __syncthreads();   // all waves done with K-loop (h_lds dead)

  // stage 1: waves 0-3 write their partial
  if (wave < 4) {
    float* pw = part[wave];
    #pragma unroll
    for (int m = 0; m < 4; ++m)
      #pragma unroll
      for (int n = 0; n < 4; ++n)
        #pragma unroll
        for (int r = 0; r < 4; ++r)
          pw[(m * 16 + kgrp * 4 + r) * P_STRIDE + n * 16 + mrow] = acc[m][n][r];
  }
  __syncthreads();

  // stage 2: waves 4-7 accumulate into buffer (wave-4)
  if (wave >= 4) {
    float* pw = part[wave - 4];
    #pragma unroll
    for (int m = 0; m < 4; ++m)
      #pragma unroll
      for (int n = 0; n < 4; ++n)
        #pragma unroll
        for (int r = 0; r < 4; ++r)
          pw[(m * 16 + kgrp * 4 + r) * P_STRIDE + n * 16 + mrow] += acc[m][n][r];
  }
  __syncthreads();

  // stage 3: all 512 threads sum 4 buffers; thread: row=tid>>3, 8 cols.
  {
    int row = tid >> 3;
    int cb  = (tid & 7) * 8;
    const float* p0 = part[0] + row * P_STRIDE + cb;
    float s[8];
    #pragma unroll
    for (int j = 0; j < 8; ++j) s[j] = p0[j];
    #pragma unroll
    for (int w = 1; w < 4; ++w)
      #pragma unroll
      for (int j = 0; j < 8; ++j) s[j] += p0[w * P_BUF + j];
    float* op = out + (rowblk + row) * 64 + cb;
    *(f32x4*)(op)     = (f32x4){s[0], s[1], s[2], s[3]};
    *(f32x4*)(op + 4) = (f32x4){s[4], s[5], s[6], s[7]};
  }
}

extern "C" void kernel_launch(void* const* d_in, const int* in_sizes, int n_in,
                              void* d_out, int out_size, void* d_ws, size_t ws_size,
                              hipStream_t stream) {
  const float* x    = (const float*)d_in[0];
  const float* grid = (const float*)d_in[1];
  const float* W1   = (const float*)d_in[2];
  const float* b1   = (const float*)d_in[3];
  const float* W2   = (const float*)d_in[4];
  const float* b2   = (const float*)d_in[5];
  float* out = (float*)d_out;
  _Float16* wsB = (_Float16*)d_ws;   // needs 65*4096*2 = 532480 bytes

  hipLaunchKernelGGL(prep_kernel, dim3((NCHUNK * 4096 + 255) / 256), dim3(256), 0, stream,
                     W2, b2, wsB);
  hipLaunchKernelGGL(main_kernel, dim3(N_PTS / ROWS), dim3(512), 0, stream,
                     x, grid, W1, b1, wsB, out);
}

// Round 4
// 41.455 us; speedup vs baseline: 2.7008x; 2.7008x over previous
//
#include <hip/hip_runtime.h>
#include <hip/hip_bf16.h>
#include <hip/hip_fp16.h>

typedef _Float16 f16x8 __attribute__((ext_vector_type(8)));
typedef float f32x4 __attribute__((ext_vector_type(4)));

#define N_PTS 32768
#define NCHUNK 65       // 64 h-chunks + 1 bias chunk (h == 1)
#define ROWS 64         // rows per block
#define P_STRIDE 65     // odd stride: scalar reduce traffic <=2-way bank alias
#define P_BUF (ROWS * P_STRIDE)

// ---- prep: convert W2 (fp32 [4096][64]) and b2 (fp32 [4096]) into f16
// fragment-major layout in ws. Dest-coalesced: thread d writes one 16B chunk
// (8 consecutive f16), reading 8 fp32 at stride 64.
//   d = ((c*2+s)*4+nt)*64 + lane ; j=0..7:
//   wsB[d*8+j] = Wf[c*64 + s*32 + ((lane>>4)&3)*8 + j][nt*16 + (lane&15)]
//   Wf[kk][o] = W2[kk*64+o] for kk<4096 ; bias rows: b2[kl*64+o] (chunk c==64)
__global__ void prep_kernel(const float* __restrict__ W2,
                            const float* __restrict__ b2,
                            _Float16* __restrict__ wsB) {
    int d = blockIdx.x * blockDim.x + threadIdx.x;
    if (d >= NCHUNK * 512) return;       // 65*4096/8 dest chunks
    int lane = d & 63;
    int nt   = (d >> 6) & 3;
    int s    = (d >> 8) & 1;
    int c    = d >> 9;
    int o      = nt * 16 + (lane & 15);
    int klbase = s * 32 + ((lane >> 4) & 3) * 8;
    const float* src = (c < 64) ? (W2 + (c * 64 + klbase) * 64 + o)
                                : (b2 + klbase * 64 + o);
    f16x8 v;
    #pragma unroll
    for (int j = 0; j < 8; ++j) v[j] = (_Float16)src[j * 64];
    *(f16x8*)(wsB + d * 8) = v;
}

// ---- main fused kernel ----
// 512 blocks x 512 threads (8 waves). Block owns 64 rows; waves K-split the
// 65 chunks 8-way (wave w: c = w, w+8, ...), partials reduced via LDS 2-stage.
// launch_bounds(512,2): VGPR cap >=128 under either 2nd-arg interpretation --
// natural ~104 VGPR fits, no spill (R3's (512,4) forced 64 VGPR -> scratch).
__global__ __launch_bounds__(512, 2) void main_kernel(
    const float* __restrict__ x, const float* __restrict__ gridp,
    const float* __restrict__ W1, const float* __restrict__ b1,
    const _Float16* __restrict__ wsB, float* __restrict__ out) {

  __shared__ _Float16 h_lds[ROWS][66];   // 8448 B
  __shared__ float part[4][P_BUF];       // 66560 B ; total 75008 (2 blocks/CU)

  const int tid  = threadIdx.x;
  const int lane = tid & 63;
  const int wave = tid >> 6;
  const int rowblk = blockIdx.x * ROWS;

  // phase 1: h[row][k] = gelu(grid @ W1 + b1). 8 threads/row, 8 k each.
  {
    int row = tid >> 3;
    int kb  = (tid & 7) * 8;
    int r = rowblk + row;
    float g0 = gridp[r * 3 + 0], g1 = gridp[r * 3 + 1], g2 = gridp[r * 3 + 2];
    f32x4 wa0 = *(const f32x4*)(W1 + kb),       wa1 = *(const f32x4*)(W1 + kb + 4);
    f32x4 wb0 = *(const f32x4*)(W1 + 64 + kb),  wb1 = *(const f32x4*)(W1 + 64 + kb + 4);
    f32x4 wc0 = *(const f32x4*)(W1 + 128 + kb), wc1 = *(const f32x4*)(W1 + 128 + kb + 4);
    f32x4 bb0 = *(const f32x4*)(b1 + kb),       bb1 = *(const f32x4*)(b1 + kb + 4);
    #pragma unroll
    for (int q = 0; q < 8; ++q) {
      float v = (q < 4)
        ? g0 * wa0[q] + g1 * wb0[q] + g2 * wc0[q] + bb0[q]
        : g0 * wa1[q - 4] + g1 * wb1[q - 4] + g2 * wc1[q - 4] + bb1[q - 4];
      float h = 0.5f * v * (1.0f + erff(v * 0.7071067811865476f));
      h_lds[row][kb + q] = (_Float16)h;
    }
    if ((tid & 7) == 7) h_lds[row][64] = (_Float16)1.0f;  // bias chunk: h == 1
  }
  __syncthreads();

  const int mrow = lane & 15;        // A row within 16-tile / D col
  const int kgrp = lane >> 4;        // 0..3

  // x fragments: xf[m][s][j] = x[row, s*32 + kgrp*8 + j]  (fixed across K loop)
  f16x8 xf[4][2];
  #pragma unroll
  for (int m = 0; m < 4; ++m) {
    #pragma unroll
    for (int s = 0; s < 2; ++s) {
      const float* xp = x + (rowblk + m * 16 + mrow) * 64 + s * 32 + kgrp * 8;
      f16x8 v;
      #pragma unroll
      for (int j = 0; j < 8; ++j) v[j] = (_Float16)xp[j];
      xf[m][s] = v;
    }
  }

  f32x4 acc[4][4];
  #pragma unroll
  for (int m = 0; m < 4; ++m)
    #pragma unroll
    for (int n = 0; n < 4; ++n)
      acc[m][n] = (f32x4){0.f, 0.f, 0.f, 0.f};

  const _Float16* bp = wsB + lane * 8;   // + (c*8 + q)*512 elements

  auto LOADB = [&](f16x8* b, int c) {
    #pragma unroll
    for (int q = 0; q < 8; ++q)
      b[q] = *(const f16x8*)(bp + (c * 8 + q) * 512);
  };
  auto COMPUTE = [&](const f16x8* b, int c) {
    #pragma unroll
    for (int m = 0; m < 4; ++m) {
      _Float16 hh = h_lds[m * 16 + mrow][c];
      f16x8 hs = {hh, hh, hh, hh, hh, hh, hh, hh};
      f16x8 a0 = xf[m][0] * hs;   // v_pk_mul_f16: A-frag = h_k * x-frag
      f16x8 a1 = xf[m][1] * hs;
      #pragma unroll
      for (int n = 0; n < 4; ++n) {
        acc[m][n] = __builtin_amdgcn_mfma_f32_16x16x32_f16(a0, b[n],     acc[m][n], 0, 0, 0);
        acc[m][n] = __builtin_amdgcn_mfma_f32_16x16x32_f16(a1, b[4 + n], acc[m][n], 0, 0, 0);
      }
    }
  };

  // K-split: wave w handles chunks c = w, w+8, ... (< 65). wave0 gets 9.
  const int nch = (wave == 0) ? 9 : 8;
  f16x8 bufA[8], bufB[8];
  LOADB(bufA, wave);
  int i = 1;
  for (; i + 1 < nch; i += 2) {
    LOADB(bufB, wave + 8 * i);
    COMPUTE(bufA, wave + 8 * (i - 1));
    LOADB(bufA, wave + 8 * (i + 1));   // max c = 64 (wave 0) : in range
    COMPUTE(bufB, wave + 8 * i);
  }
  if (i < nch) {                       // nch even (8): tail pair
    LOADB(bufB, wave + 8 * i);
    COMPUTE(bufA, wave + 8 * (i - 1));
    COMPUTE(bufB, wave + 8 * i);
  } else {                             // nch odd (9, wave 0)
    COMPUTE(bufA, wave + 8 * (nch - 1));
  }

  __syncthreads();   // all waves done with K-loop (h_lds dead)

  // stage 1: waves 0-3 write their partial
  if (wave < 4) {
    float* pw = part[wave];
    #pragma unroll
    for (int m = 0; m < 4; ++m)
      #pragma unroll
      for (int n = 0; n < 4; ++n)
        #pragma unroll
        for (int r = 0; r < 4; ++r)
          pw[(m * 16 + kgrp * 4 + r) * P_STRIDE + n * 16 + mrow] = acc[m][n][r];
  }
  __syncthreads();

  // stage 2: waves 4-7 accumulate into buffer (wave-4)
  if (wave >= 4) {
    float* pw = part[wave - 4];
    #pragma unroll
    for (int m = 0; m < 4; ++m)
      #pragma unroll
      for (int n = 0; n < 4; ++n)
        #pragma unroll
        for (int r = 0; r < 4; ++r)
          pw[(m * 16 + kgrp * 4 + r) * P_STRIDE + n * 16 + mrow] += acc[m][n][r];
  }
  __syncthreads();

  // stage 3: all 512 threads sum 4 buffers; thread: row=tid>>3, 8 cols.
  {
    int row = tid >> 3;
    int cb  = (tid & 7) * 8;
    const float* p0 = part[0] + row * P_STRIDE + cb;
    float s[8];
    #pragma unroll
    for (int j = 0; j < 8; ++j) s[j] = p0[j];
    #pragma unroll
    for (int w = 1; w < 4; ++w)
      #pragma unroll
      for (int j = 0; j < 8; ++j) s[j] += p0[w * P_BUF + j];
    float* op = out + (rowblk + row) * 64 + cb;
    *(f32x4*)(op)     = (f32x4){s[0], s[1], s[2], s[3]};
    *(f32x4*)(op + 4) = (f32x4){s[4], s[5], s[6], s[7]};
  }
}

extern "C" void kernel_launch(void* const* d_in, const int* in_sizes, int n_in,
                              void* d_out, int out_size, void* d_ws, size_t ws_size,
                              hipStream_t stream) {
  const float* x    = (const float*)d_in[0];
  const float* grid = (const float*)d_in[1];
  const float* W1   = (const float*)d_in[2];
  const float* b1   = (const float*)d_in[3];
  const float* W2   = (const float*)d_in[4];
  const float* b2   = (const float*)d_in[5];
  float* out = (float*)d_out;
  _Float16* wsB = (_Float16*)d_ws;   // needs 65*4096*2 = 532480 bytes

  hipLaunchKernelGGL(prep_kernel, dim3((NCHUNK * 512 + 255) / 256), dim3(256), 0, stream,
                     W2, b2, wsB);
  hipLaunchKernelGGL(main_kernel, dim3(N_PTS / ROWS), dim3(512), 0, stream,
                     x, grid, W1, b1, wsB, out);
}

// Round 5
// 36.335 us; speedup vs baseline: 3.0814x; 1.1409x over previous
//
#include <hip/hip_runtime.h>
#include <hip/hip_bf16.h>
#include <hip/hip_fp16.h>

typedef _Float16 f16x8 __attribute__((ext_vector_type(8)));
typedef float f32x4 __attribute__((ext_vector_type(4)));

#define N_PTS 32768
#define NCHUNK 65       // 64 h-chunks + 1 bias chunk (h == 1)
#define ROWS_BLK 128    // rows per block (2 M-groups of 64)
#define H_STRIDE 72     // f16; 144 B rows -> 16B-aligned b128 stores, 2-way alias max
#define P_STRIDE 68     // f32; 272 B rows -> 16B-aligned, 2-way alias max (free)

// ---- prep: convert W2 (fp32 [4096][64]) and b2 (fp32 [4096]) into f16
// fragment-major layout in ws. Dest-coalesced: thread d writes one 16B chunk
// (8 consecutive f16), reading 8 fp32 at stride 64.
//   d = ((c*2+s)*4+nt)*64 + lane ; j=0..7:
//   wsB[d*8+j] = Wf[c*64 + s*32 + ((lane>>4)&3)*8 + j][nt*16 + (lane&15)]
//   Wf[kk][o] = W2[kk*64+o] for kk<4096 ; bias rows: b2[kl*64+o] (chunk c==64)
__global__ void prep_kernel(const float* __restrict__ W2,
                            const float* __restrict__ b2,
                            _Float16* __restrict__ wsB) {
    int d = blockIdx.x * blockDim.x + threadIdx.x;
    if (d >= NCHUNK * 512) return;       // 65*4096/8 dest chunks
    int lane = d & 63;
    int nt   = (d >> 6) & 3;
    int s    = (d >> 8) & 1;
    int c    = d >> 9;
    int o      = nt * 16 + (lane & 15);
    int klbase = s * 32 + ((lane >> 4) & 3) * 8;
    const float* src = (c < 64) ? (W2 + (c * 64 + klbase) * 64 + o)
                                : (b2 + klbase * 64 + o);
    f16x8 v;
    #pragma unroll
    for (int j = 0; j < 8; ++j) v[j] = (_Float16)src[j * 64];
    *(f16x8*)(wsB + d * 8) = v;
}

// ---- main fused kernel ----
// 256 blocks x 512 threads (8 waves). Block owns 128 rows as 2 M-groups of 64;
// within each group, 4 waves K-split the 65 chunks (kw: c = kw, kw+4, ...).
// Halves B L2-traffic vs 64-row blocks: 256 x 532 KB = 136 MB.
__global__ __launch_bounds__(512) void main_kernel(
    const float* __restrict__ x, const float* __restrict__ gridp,
    const float* __restrict__ W1, const float* __restrict__ b1,
    const _Float16* __restrict__ wsB, float* __restrict__ out) {

  __shared__ _Float16 h_lds[ROWS_BLK][H_STRIDE];      // 18432 B
  __shared__ float part[2][2][64 * P_STRIDE];         // 4 x 17408 = 69632 B
  // total 88064 B -> 1 block/CU, 8 waves/CU

  const int tid  = threadIdx.x;
  const int lane = tid & 63;
  const int wave = tid >> 6;
  const int group = wave >> 2;       // M-group: 0 -> rows 0-63, 1 -> rows 64-127
  const int kw    = wave & 3;        // K-split index within group
  const int rowblk = blockIdx.x * ROWS_BLK;
  const int growbase = rowblk + group * 64;

  // phase 1: h[row][k] = gelu(grid @ W1 + b1). 4 threads/row, 16 k each.
  {
    int row = tid >> 2;              // 0..127
    int kb  = (tid & 3) * 16;
    int r = rowblk + row;
    float g0 = gridp[r * 3 + 0], g1 = gridp[r * 3 + 1], g2 = gridp[r * 3 + 2];
    f16x8 h0, h1;
    #pragma unroll
    for (int q = 0; q < 16; ++q) {
      int k = kb + q;
      float v = g0 * W1[k] + g1 * W1[64 + k] + g2 * W1[128 + k] + b1[k];
      float h = 0.5f * v * (1.0f + erff(v * 0.7071067811865476f));
      if (q < 8) h0[q] = (_Float16)h; else h1[q - 8] = (_Float16)h;
    }
    *(f16x8*)(&h_lds[row][kb])     = h0;   // 144 B row stride: 16B-aligned
    *(f16x8*)(&h_lds[row][kb + 8]) = h1;
    if ((tid & 3) == 3) h_lds[row][64] = (_Float16)1.0f;  // bias chunk: h == 1
  }
  __syncthreads();

  const int mrow = lane & 15;        // A row within 16-tile / D col
  const int kgrp = lane >> 4;        // 0..3

  // x fragments: xf[m][s][j] = x[growbase + m*16+mrow, s*32 + kgrp*8 + j]
  f16x8 xf[4][2];
  #pragma unroll
  for (int m = 0; m < 4; ++m) {
    #pragma unroll
    for (int s = 0; s < 2; ++s) {
      const float* xp = x + (growbase + m * 16 + mrow) * 64 + s * 32 + kgrp * 8;
      f16x8 v;
      #pragma unroll
      for (int j = 0; j < 8; ++j) v[j] = (_Float16)xp[j];
      xf[m][s] = v;
    }
  }

  f32x4 acc[4][4];
  #pragma unroll
  for (int m = 0; m < 4; ++m)
    #pragma unroll
    for (int n = 0; n < 4; ++n)
      acc[m][n] = (f32x4){0.f, 0.f, 0.f, 0.f};

  const _Float16* bp = wsB + lane * 8;   // + (c*8 + q)*512 elements

  auto LOADB = [&](f16x8* b, int c) {
    #pragma unroll
    for (int q = 0; q < 8; ++q)
      b[q] = *(const f16x8*)(bp + (c * 8 + q) * 512);
  };
  auto COMPUTE = [&](const f16x8* b, int c) {
    #pragma unroll
    for (int m = 0; m < 4; ++m) {
      _Float16 hh = h_lds[group * 64 + m * 16 + mrow][c];
      f16x8 hs = {hh, hh, hh, hh, hh, hh, hh, hh};
      f16x8 a0 = xf[m][0] * hs;   // v_pk_mul_f16: A-frag = h_k * x-frag
      f16x8 a1 = xf[m][1] * hs;
      #pragma unroll
      for (int n = 0; n < 4; ++n) {
        acc[m][n] = __builtin_amdgcn_mfma_f32_16x16x32_f16(a0, b[n],     acc[m][n], 0, 0, 0);
        acc[m][n] = __builtin_amdgcn_mfma_f32_16x16x32_f16(a1, b[4 + n], acc[m][n], 0, 0, 0);
      }
    }
  };

  // K-split: kw handles chunks c = kw, kw+4, ... (< 65). kw==0 gets 17.
  const int nch = (kw == 0) ? 17 : 16;
  f16x8 bufA[8], bufB[8];
  LOADB(bufA, kw);
  int i = 1;
  for (; i + 1 < nch; i += 2) {
    LOADB(bufB, kw + 4 * i);
    COMPUTE(bufA, kw + 4 * (i - 1));
    LOADB(bufA, kw + 4 * (i + 1));   // max c = 64 (kw 0) : in range
    COMPUTE(bufB, kw + 4 * i);
  }
  if (i < nch) {                       // nch even (16): tail pair
    LOADB(bufB, kw + 4 * i);
    COMPUTE(bufA, kw + 4 * (i - 1));
    COMPUTE(bufB, kw + 4 * i);
  } else {                             // nch odd (17, kw 0)
    COMPUTE(bufA, kw + 4 * (nch - 1));
  }

  __syncthreads();

  // stage 1: kw 0-1 write partials (both groups concurrently, disjoint bufs)
  if (kw < 2) {
    float* pw = part[group][kw];
    #pragma unroll
    for (int m = 0; m < 4; ++m)
      #pragma unroll
      for (int n = 0; n < 4; ++n)
        #pragma unroll
        for (int r = 0; r < 4; ++r)
          pw[(m * 16 + kgrp * 4 + r) * P_STRIDE + n * 16 + mrow] = acc[m][n][r];
  }
  __syncthreads();

  // stage 2: kw 2-3 accumulate into buffer kw-2
  if (kw >= 2) {
    float* pw = part[group][kw - 2];
    #pragma unroll
    for (int m = 0; m < 4; ++m)
      #pragma unroll
      for (int n = 0; n < 4; ++n)
        #pragma unroll
        for (int r = 0; r < 4; ++r)
          pw[(m * 16 + kgrp * 4 + r) * P_STRIDE + n * 16 + mrow] += acc[m][n][r];
  }
  __syncthreads();

  // stage 3: all 512 threads sum the 2 buffers of their row's group; store.
  {
    int row = tid >> 2;               // 0..127
    int cb  = (tid & 3) * 16;
    int g2 = row >> 6, r2 = row & 63;
    const float* p0 = part[g2][0] + r2 * P_STRIDE + cb;
    const float* p1 = part[g2][1] + r2 * P_STRIDE + cb;
    float* op = out + (rowblk + row) * 64 + cb;
    #pragma unroll
    for (int j = 0; j < 4; ++j) {
      f32x4 s = *(const f32x4*)(p0 + j * 4);
      s += *(const f32x4*)(p1 + j * 4);
      *(f32x4*)(op + j * 4) = s;
    }
  }
}

extern "C" void kernel_launch(void* const* d_in, const int* in_sizes, int n_in,
                              void* d_out, int out_size, void* d_ws, size_t ws_size,
                              hipStream_t stream) {
  const float* x    = (const float*)d_in[0];
  const float* grid = (const float*)d_in[1];
  const float* W1   = (const float*)d_in[2];
  const float* b1   = (const float*)d_in[3];
  const float* W2   = (const float*)d_in[4];
  const float* b2   = (const float*)d_in[5];
  float* out = (float*)d_out;
  _Float16* wsB = (_Float16*)d_ws;   // needs 65*4096*2 = 532480 bytes

  hipLaunchKernelGGL(prep_kernel, dim3((NCHUNK * 512 + 255) / 256), dim3(256), 0, stream,
                     W2, b2, wsB);
  hipLaunchKernelGGL(main_kernel, dim3(N_PTS / ROWS_BLK), dim3(512), 0, stream,
                     x, grid, W1, b1, wsB, out);
}

// Round 6
// 33.089 us; speedup vs baseline: 3.3837x; 1.0981x over previous
//
#include <hip/hip_runtime.h>
#include <hip/hip_bf16.h>
#include <hip/hip_fp16.h>

typedef _Float16 f16x8 __attribute__((ext_vector_type(8)));
typedef float f32x4 __attribute__((ext_vector_type(4)));

#define N_PTS 32768
#define NCHUNK 65       // 64 h-chunks + 1 bias chunk (h == 1)
#define ROWS 64         // rows per block
#define H_STRIDE 72     // f16; 144 B rows: 16B-aligned b128, reads 2-way max
#define X_STRIDE 72     // f16; same
#define P_STRIDE 68     // f32; 272 B rows: 16B-aligned, 2-way alias max

// ---- prep: repack W2 (fp32 [4096][64]) + b2 (fp32 [4096]) into f16 MFMA
// fragment layout. One block per chunk c (64 K-rows x 64 cols).
//   dest: wsB[c*4096 + (q*64+lane)*8 + j] = Wf[c*64 + klbase+j][o]
//         klbase = (q>>2)*32 + ((lane>>4)&3)*8 ; o = (q&3)*16 + (lane&15)
//   Wf[kk][o] = W2[kk*64+o] (chunk 64 = b2 rows). All global I/O coalesced;
//   the transpose happens in LDS.
__global__ __launch_bounds__(256) void prep_kernel(
    const float* __restrict__ W2, const float* __restrict__ b2,
    _Float16* __restrict__ wsB) {
  __shared__ _Float16 w_lds[64][X_STRIDE];
  const int c   = blockIdx.x;
  const int tid = threadIdx.x;
  // phase A: coalesced load of 16 consecutive f32 -> f16 -> LDS
  {
    const float* src = (c < 64) ? (W2 + c * 4096 + tid * 16) : (b2 + tid * 16);
    int kl = tid >> 2, o = (tid & 3) * 16;
    f16x8 v0, v1;
    #pragma unroll
    for (int j = 0; j < 8; ++j) {
      v0[j] = (_Float16)src[j];
      v1[j] = (_Float16)src[8 + j];
    }
    *(f16x8*)(&w_lds[kl][o])     = v0;
    *(f16x8*)(&w_lds[kl][o + 8]) = v1;
  }
  __syncthreads();
  // phase B: assemble dest f16x8 (column of 8 K-rows) and write coalesced
  #pragma unroll
  for (int u = 0; u < 2; ++u) {
    int t = tid + u * 256;           // dest chunk index within c: 0..511
    int q = t >> 6, lane = t & 63;
    int klbase = (q >> 2) * 32 + ((lane >> 4) & 3) * 8;
    int o      = (q & 3) * 16 + (lane & 15);
    f16x8 v;
    #pragma unroll
    for (int j = 0; j < 8; ++j) v[j] = w_lds[klbase + j][o];
    *(f16x8*)(wsB + c * 4096 + t * 8) = v;
  }
}

// ---- main fused kernel ----
// 512 blocks x 256 threads (4 waves), 2 blocks/CU. Block owns 64 rows; waves
// K-split the 65 chunks (wave w: c = w, w+4, ...), partials reduced via LDS.
__global__ __launch_bounds__(256) void main_kernel(
    const float* __restrict__ x, const float* __restrict__ gridp,
    const float* __restrict__ W1, const float* __restrict__ b1,
    const _Float16* __restrict__ wsB, float* __restrict__ out) {

  __shared__ _Float16 h_lds[ROWS][H_STRIDE];   // 9216 B
  __shared__ float part[4][ROWS * P_STRIDE];   // 69632 B; total 78848 -> 2/CU
  _Float16* x_lds = (_Float16*)&part[0][0];    // [64][X_STRIDE]; dead before part

  const int tid  = threadIdx.x;
  const int lane = tid & 63;
  const int wave = tid >> 6;
  const int rowblk = blockIdx.x * ROWS;

  // phase 0: issue coalesced x-tile load (16 consecutive f32 per thread)
  const float* xsrc = x + rowblk * 64 + tid * 16;
  f32x4 xr0 = *(const f32x4*)(xsrc);
  f32x4 xr1 = *(const f32x4*)(xsrc + 4);
  f32x4 xr2 = *(const f32x4*)(xsrc + 8);
  f32x4 xr3 = *(const f32x4*)(xsrc + 12);

  // phase 1: h[row][k] = gelu(grid @ W1 + b1). 4 threads/row, 16 k each.
  {
    int row = tid >> 2;
    int kb  = (tid & 3) * 16;
    int r = rowblk + row;
    float g0 = gridp[r * 3 + 0], g1 = gridp[r * 3 + 1], g2 = gridp[r * 3 + 2];
    f16x8 h0, h1;
    #pragma unroll
    for (int q = 0; q < 16; ++q) {
      int k = kb + q;
      float v = g0 * W1[k] + g1 * W1[64 + k] + g2 * W1[128 + k] + b1[k];
      float h = 0.5f * v * (1.0f + erff(v * 0.7071067811865476f));
      if (q < 8) h0[q] = (_Float16)h; else h1[q - 8] = (_Float16)h;
    }
    *(f16x8*)(&h_lds[row][kb])     = h0;
    *(f16x8*)(&h_lds[row][kb + 8]) = h1;
    if ((tid & 3) == 3) h_lds[row][64] = (_Float16)1.0f;  // bias chunk: h == 1
  }

  // phase 2: x -> f16 -> LDS (coalesced-in, b128 LDS writes)
  {
    int row = tid >> 2, o = (tid & 3) * 16;
    f16x8 v0, v1;
    #pragma unroll
    for (int j = 0; j < 4; ++j) {
      v0[j]     = (_Float16)xr0[j];
      v0[4 + j] = (_Float16)xr1[j];
      v1[j]     = (_Float16)xr2[j];
      v1[4 + j] = (_Float16)xr3[j];
    }
    *(f16x8*)(&x_lds[row * X_STRIDE + o])     = v0;
    *(f16x8*)(&x_lds[row * X_STRIDE + o + 8]) = v1;
  }
  __syncthreads();

  const int mrow = lane & 15;        // A row within 16-tile / D col
  const int kgrp = lane >> 4;        // 0..3

  const _Float16* bp = wsB + lane * 8;   // + (c*8 + q)*512 elements

  auto LOADB = [&](f16x8* b, int c) {
    #pragma unroll
    for (int q = 0; q < 8; ++q)
      b[q] = *(const f16x8*)(bp + (c * 8 + q) * 512);
  };

  // issue first B batch before LDS fragment reads (overlap global latency)
  f16x8 bufA[8], bufB[8];
  LOADB(bufA, wave);

  // x fragments from LDS: xf[m][s] = x_lds[m*16+mrow][s*32+kgrp*8 ..+8]
  f16x8 xf[4][2];
  #pragma unroll
  for (int m = 0; m < 4; ++m)
    #pragma unroll
    for (int s = 0; s < 2; ++s)
      xf[m][s] = *(const f16x8*)(&x_lds[(m * 16 + mrow) * X_STRIDE + s * 32 + kgrp * 8]);

  f32x4 acc[4][4];
  #pragma unroll
  for (int m = 0; m < 4; ++m)
    #pragma unroll
    for (int n = 0; n < 4; ++n)
      acc[m][n] = (f32x4){0.f, 0.f, 0.f, 0.f};

  auto COMPUTE = [&](const f16x8* b, int c) {
    #pragma unroll
    for (int m = 0; m < 4; ++m) {
      _Float16 hh = h_lds[m * 16 + mrow][c];
      f16x8 hs = {hh, hh, hh, hh, hh, hh, hh, hh};
      f16x8 a0 = xf[m][0] * hs;   // v_pk_mul_f16: A-frag = h_k * x-frag
      f16x8 a1 = xf[m][1] * hs;
      #pragma unroll
      for (int n = 0; n < 4; ++n) {
        acc[m][n] = __builtin_amdgcn_mfma_f32_16x16x32_f16(a0, b[n],     acc[m][n], 0, 0, 0);
        acc[m][n] = __builtin_amdgcn_mfma_f32_16x16x32_f16(a1, b[4 + n], acc[m][n], 0, 0, 0);
      }
    }
  };

  // K-split: wave w handles chunks c = w, w+4, ... (< 65). wave0 gets 17.
  const int nch = (wave == 0) ? 17 : 16;
  int i = 1;
  for (; i + 1 < nch; i += 2) {
    LOADB(bufB, wave + 4 * i);
    COMPUTE(bufA, wave + 4 * (i - 1));
    LOADB(bufA, wave + 4 * (i + 1));   // max c = 64 (wave 0): in range
    COMPUTE(bufB, wave + 4 * i);
  }
  if (i < nch) {                       // nch even (16): tail pair
    LOADB(bufB, wave + 4 * i);
    COMPUTE(bufA, wave + 4 * (i - 1));
    COMPUTE(bufB, wave + 4 * i);
  } else {                             // nch odd (17, wave 0)
    COMPUTE(bufA, wave + 4 * (nch - 1));
  }

  __syncthreads();   // K-loop done everywhere; x_lds dead -> part may be written

  // one-stage reduce: every wave writes its partial buffer...
  {
    float* pw = part[wave];
    #pragma unroll
    for (int m = 0; m < 4; ++m)
      #pragma unroll
      for (int n = 0; n < 4; ++n)
        #pragma unroll
        for (int r = 0; r < 4; ++r)
          pw[(m * 16 + kgrp * 4 + r) * P_STRIDE + n * 16 + mrow] = acc[m][n][r];
  }
  __syncthreads();

  // ...then all 256 threads sum 4 buffers and store (4 threads/row, 16 cols)
  {
    int row = tid >> 2;
    int cb  = (tid & 3) * 16;
    const float* p0 = part[0] + row * P_STRIDE + cb;
    float* op = out + (rowblk + row) * 64 + cb;
    #pragma unroll
    for (int j = 0; j < 4; ++j) {
      f32x4 s = *(const f32x4*)(p0 + j * 4);
      #pragma unroll
      for (int w = 1; w < 4; ++w)
        s += *(const f32x4*)(p0 + w * (ROWS * P_STRIDE) + j * 4);
      *(f32x4*)(op + j * 4) = s;
    }
  }
}

extern "C" void kernel_launch(void* const* d_in, const int* in_sizes, int n_in,
                              void* d_out, int out_size, void* d_ws, size_t ws_size,
                              hipStream_t stream) {
  const float* x    = (const float*)d_in[0];
  const float* grid = (const float*)d_in[1];
  const float* W1   = (const float*)d_in[2];
  const float* b1   = (const float*)d_in[3];
  const float* W2   = (const float*)d_in[4];
  const float* b2   = (const float*)d_in[5];
  float* out = (float*)d_out;
  _Float16* wsB = (_Float16*)d_ws;   // needs 65*4096*2 = 532480 bytes

  hipLaunchKernelGGL(prep_kernel, dim3(NCHUNK), dim3(256), 0, stream,
                     W2, b2, wsB);
  hipLaunchKernelGGL(main_kernel, dim3(N_PTS / ROWS), dim3(256), 0, stream,
                     x, grid, W1, b1, wsB, out);
}

// Round 7
// 31.901 us; speedup vs baseline: 3.5097x; 1.0372x over previous
//
#include <hip/hip_runtime.h>
#include <hip/hip_bf16.h>
#include <hip/hip_fp16.h>

typedef _Float16 f16x8 __attribute__((ext_vector_type(8)));
typedef _Float16 f16x4v __attribute__((ext_vector_type(4)));
typedef float f32x4 __attribute__((ext_vector_type(4)));

#define N_PTS 32768
#define NCHUNK 65       // 64 h-chunks + 1 bias chunk (h == 1)
#define ROWS 64         // rows per block
#define H_STRIDE 72     // f16; 144 B rows: 16B-aligned b128, reads 2-way max
#define X_STRIDE 72     // f16; same
#define P_STRIDE 68     // f32; 272 B rows: 16B-aligned, 2-way alias max

// ---- prep: repack W2 (fp32 [4096][64]) + b2 (fp32 [4096]) into f16 MFMA
// fragment layout. One block per chunk c (64 K-rows x 64 cols).
//   dest: wsB[c*4096 + (q*64+lane)*8 + j] = Wf[c*64 + klbase+j][o]
//         klbase = (q>>2)*32 + ((lane>>4)&3)*8 ; o = (q&3)*16 + (lane&15)
//   Wf[kk][o] = W2[kk*64+o] (chunk 64 = b2 rows). All global I/O coalesced;
//   the transpose happens in LDS.
__global__ __launch_bounds__(256) void prep_kernel(
    const float* __restrict__ W2, const float* __restrict__ b2,
    _Float16* __restrict__ wsB) {
  __shared__ _Float16 w_lds[64][X_STRIDE];
  const int c   = blockIdx.x;
  const int tid = threadIdx.x;
  {
    const float* src = (c < 64) ? (W2 + c * 4096 + tid * 16) : (b2 + tid * 16);
    int kl = tid >> 2, o = (tid & 3) * 16;
    f16x8 v0, v1;
    #pragma unroll
    for (int j = 0; j < 8; ++j) {
      v0[j] = (_Float16)src[j];
      v1[j] = (_Float16)src[8 + j];
    }
    *(f16x8*)(&w_lds[kl][o])     = v0;
    *(f16x8*)(&w_lds[kl][o + 8]) = v1;
  }
  __syncthreads();
  #pragma unroll
  for (int u = 0; u < 2; ++u) {
    int t = tid + u * 256;           // dest chunk index within c: 0..511
    int q = t >> 6, lane = t & 63;
    int klbase = (q >> 2) * 32 + ((lane >> 4) & 3) * 8;
    int o      = (q & 3) * 16 + (lane & 15);
    f16x8 v;
    #pragma unroll
    for (int j = 0; j < 8; ++j) v[j] = w_lds[klbase + j][o];
    *(f16x8*)(wsB + c * 4096 + t * 8) = v;
  }
}

// ---- main fused kernel ----
// 512 blocks x 256 threads (4 waves), 2 blocks/CU. Block owns 64 rows; waves
// K-split the 65 chunks (wave w: c = w, w+4, ...; bias chunk 64 -> wave 0).
// K-loop: TRIPLE-buffered B (2 chunks of prefetch depth, 24 outstanding
// dwordx4) + rolling register prefetch of next chunk's 4 h values, so no
// LDS read sits on the MFMA critical path.
__global__ __launch_bounds__(256) void main_kernel(
    const float* __restrict__ x, const float* __restrict__ gridp,
    const float* __restrict__ W1, const float* __restrict__ b1,
    const _Float16* __restrict__ wsB, float* __restrict__ out) {

  __shared__ _Float16 h_lds[ROWS][H_STRIDE];   // 9216 B
  __shared__ float part[4][ROWS * P_STRIDE];   // 69632 B; total 78848 -> 2/CU
  _Float16* x_lds = (_Float16*)&part[0][0];    // [64][X_STRIDE]; dead before part

  const int tid  = threadIdx.x;
  const int lane = tid & 63;
  const int wave = tid >> 6;
  const int rowblk = blockIdx.x * ROWS;

  // phase 0: issue coalesced x-tile load (16 consecutive f32 per thread)
  const float* xsrc = x + rowblk * 64 + tid * 16;
  f32x4 xr0 = *(const f32x4*)(xsrc);
  f32x4 xr1 = *(const f32x4*)(xsrc + 4);
  f32x4 xr2 = *(const f32x4*)(xsrc + 8);
  f32x4 xr3 = *(const f32x4*)(xsrc + 12);

  // phase 1: h[row][k] = gelu(grid @ W1 + b1). 4 threads/row, 16 k each.
  {
    int row = tid >> 2;
    int kb  = (tid & 3) * 16;
    int r = rowblk + row;
    float g0 = gridp[r * 3 + 0], g1 = gridp[r * 3 + 1], g2 = gridp[r * 3 + 2];
    f16x8 h0, h1;
    #pragma unroll
    for (int q = 0; q < 16; ++q) {
      int k = kb + q;
      float v = g0 * W1[k] + g1 * W1[64 + k] + g2 * W1[128 + k] + b1[k];
      float h = 0.5f * v * (1.0f + erff(v * 0.7071067811865476f));
      if (q < 8) h0[q] = (_Float16)h; else h1[q - 8] = (_Float16)h;
    }
    *(f16x8*)(&h_lds[row][kb])     = h0;
    *(f16x8*)(&h_lds[row][kb + 8]) = h1;
  }

  // phase 2: x -> f16 -> LDS (coalesced-in, b128 LDS writes)
  {
    int row = tid >> 2, o = (tid & 3) * 16;
    f16x8 v0, v1;
    #pragma unroll
    for (int j = 0; j < 4; ++j) {
      v0[j]     = (_Float16)xr0[j];
      v0[4 + j] = (_Float16)xr1[j];
      v1[j]     = (_Float16)xr2[j];
      v1[4 + j] = (_Float16)xr3[j];
    }
    *(f16x8*)(&x_lds[row * X_STRIDE + o])     = v0;
    *(f16x8*)(&x_lds[row * X_STRIDE + o + 8]) = v1;
  }
  __syncthreads();

  const int mrow = lane & 15;        // A row within 16-tile / D col
  const int kgrp = lane >> 4;        // 0..3

  const _Float16* bp = wsB + lane * 8;   // + (c*8 + q)*512 elements

  auto LOADB = [&](f16x8* b, int c) {
    #pragma unroll
    for (int q = 0; q < 8; ++q)
      b[q] = *(const f16x8*)(bp + (c * 8 + q) * 512);
  };
  auto LOADH = [&](int c) -> f16x4v {
    f16x4v h;
    #pragma unroll
    for (int m = 0; m < 4; ++m) h[m] = h_lds[m * 16 + mrow][c];
    return h;
  };

  // issue the 3-deep B prefetch + h prefetch before xf LDS reads
  f16x8 bA[8], bB[8], bC[8];
  f16x4v ha, hb, hc;
  LOADB(bA, wave);      ha = LOADH(wave);
  LOADB(bB, wave + 4);  hb = LOADH(wave + 4);
  LOADB(bC, wave + 8);  hc = LOADH(wave + 8);

  // x fragments from LDS: xf[m][s] = x_lds[m*16+mrow][s*32+kgrp*8 ..+8]
  f16x8 xf[4][2];
  #pragma unroll
  for (int m = 0; m < 4; ++m)
    #pragma unroll
    for (int s = 0; s < 2; ++s)
      xf[m][s] = *(const f16x8*)(&x_lds[(m * 16 + mrow) * X_STRIDE + s * 32 + kgrp * 8]);

  f32x4 acc[4][4];
  #pragma unroll
  for (int m = 0; m < 4; ++m)
    #pragma unroll
    for (int n = 0; n < 4; ++n)
      acc[m][n] = (f32x4){0.f, 0.f, 0.f, 0.f};

  auto COMPUTE = [&](const f16x8* b, f16x4v hv) {
    #pragma unroll
    for (int m = 0; m < 4; ++m) {
      _Float16 hh = hv[m];
      f16x8 hs = {hh, hh, hh, hh, hh, hh, hh, hh};
      f16x8 a0 = xf[m][0] * hs;   // v_pk_mul_f16: A-frag = h_k * x-frag
      f16x8 a1 = xf[m][1] * hs;
      #pragma unroll
      for (int n = 0; n < 4; ++n) {
        acc[m][n] = __builtin_amdgcn_mfma_f32_16x16x32_f16(a0, b[n],     acc[m][n], 0, 0, 0);
        acc[m][n] = __builtin_amdgcn_mfma_f32_16x16x32_f16(a1, b[4 + n], acc[m][n], 0, 0, 0);
      }
    }
  };
  auto COMPUTE_BIAS = [&](const f16x8* b) {   // h == 1: A-frag = xf directly
    #pragma unroll
    for (int m = 0; m < 4; ++m)
      #pragma unroll
      for (int n = 0; n < 4; ++n) {
        acc[m][n] = __builtin_amdgcn_mfma_f32_16x16x32_f16(xf[m][0], b[n],     acc[m][n], 0, 0, 0);
        acc[m][n] = __builtin_amdgcn_mfma_f32_16x16x32_f16(xf[m][1], b[4 + n], acc[m][n], 0, 0, 0);
      }
  };

  // 16 uniform chunks per wave (c = wave + 4*i, i=0..15), 3-stage rotation,
  // fully unrolled so all buffer references are static.
  #pragma unroll
  for (int g = 0; g < 5; ++g) {
    COMPUTE(bA, ha);
    if (3 * g + 3 < 16) { LOADB(bA, wave + 4 * (3 * g + 3)); ha = LOADH(wave + 4 * (3 * g + 3)); }
    COMPUTE(bB, hb);
    if (3 * g + 4 < 16) { LOADB(bB, wave + 4 * (3 * g + 4)); hb = LOADH(wave + 4 * (3 * g + 4)); }
    else if (wave == 0) { LOADB(bB, 64); }   // bias-chunk B, issued early
    COMPUTE(bC, hc);
    if (3 * g + 5 < 16) { LOADB(bC, wave + 4 * (3 * g + 5)); hc = LOADH(wave + 4 * (3 * g + 5)); }
  }
  COMPUTE(bA, ha);                    // chunk wave + 60
  if (wave == 0) COMPUTE_BIAS(bB);    // chunk 64 (h == 1)

  __syncthreads();   // K-loop done everywhere; x_lds dead -> part may be written

  // one-stage reduce: every wave writes its partial buffer...
  {
    float* pw = part[wave];
    #pragma unroll
    for (int m = 0; m < 4; ++m)
      #pragma unroll
      for (int n = 0; n < 4; ++n)
        #pragma unroll
        for (int r = 0; r < 4; ++r)
          pw[(m * 16 + kgrp * 4 + r) * P_STRIDE + n * 16 + mrow] = acc[m][n][r];
  }
  __syncthreads();

  // ...then all 256 threads sum 4 buffers and store (4 threads/row, 16 cols)
  {
    int row = tid >> 2;
    int cb  = (tid & 3) * 16;
    const float* p0 = part[0] + row * P_STRIDE + cb;
    float* op = out + (rowblk + row) * 64 + cb;
    #pragma unroll
    for (int j = 0; j < 4; ++j) {
      f32x4 s = *(const f32x4*)(p0 + j * 4);
      #pragma unroll
      for (int w = 1; w < 4; ++w)
        s += *(const f32x4*)(p0 + w * (ROWS * P_STRIDE) + j * 4);
      *(f32x4*)(op + j * 4) = s;
    }
  }
}

extern "C" void kernel_launch(void* const* d_in, const int* in_sizes, int n_in,
                              void* d_out, int out_size, void* d_ws, size_t ws_size,
                              hipStream_t stream) {
  const float* x    = (const float*)d_in[0];
  const float* grid = (const float*)d_in[1];
  const float* W1   = (const float*)d_in[2];
  const float* b1   = (const float*)d_in[3];
  const float* W2   = (const float*)d_in[4];
  const float* b2   = (const float*)d_in[5];
  float* out = (float*)d_out;
  _Float16* wsB = (_Float16*)d_ws;   // needs 65*4096*2 = 532480 bytes

  hipLaunchKernelGGL(prep_kernel, dim3(NCHUNK), dim3(256), 0, stream,
                     W2, b2, wsB);
  hipLaunchKernelGGL(main_kernel, dim3(N_PTS / ROWS), dim3(256), 0, stream,
                     x, grid, W1, b1, wsB, out);
}